// Round 4
// baseline (8831.948 us; speedup 1.0000x reference)
//
#include <hip/hip_runtime.h>
#include <cstdint>

typedef unsigned int   u32;
typedef unsigned long long u64;

#define N_PTS 16384
#define S_OUT 4096
#define K_NB  32
#define CAP   1024

// d_out (f32) element offsets: [4096*256 out][4096*3 centers][4096 batch]
#define OUT_CEN   1048576
#define OUT_BATCH 1060864

// ---- device-global scratch (ws_size proved unreliable in round 1) ----
__device__ int   g_idx[S_OUT];
__device__ __align__(16) float g_cen[S_OUT * 3];
__device__ int   g_cnt[S_OUT];
__device__ int   g_col[S_OUT * K_NB];

// ---------------- farthest point sampling (bitwise-exact vs numpy) ----------------
// Thread t owns points [16t, 16t+16). Distances via __f*_rn in numpy ufunc order
// ((dx*dx+dy*dy)+dz*dz) -> no FMA contraction -> bitwise match with np arbiter.
// Argmax tie-break = lowest index via packed (d2_bits<<32)|~idx u64 max-reduce
// (d2 >= 0 so float bits order as uint). 2 barriers/iter, no atomics.
__global__ __launch_bounds__(1024) void fps_kernel(const float* __restrict__ pos) {
    const int t = threadIdx.x;
    float px[16], py[16], pz[16], d[16];
    {
        const float4* p4 = (const float4*)pos;   // 192 B per thread = 12 x float4
        float f[48];
#pragma unroll
        for (int j = 0; j < 12; ++j) {
            float4 v = p4[t * 12 + j];
            f[4 * j] = v.x; f[4 * j + 1] = v.y; f[4 * j + 2] = v.z; f[4 * j + 3] = v.w;
        }
#pragma unroll
        for (int i = 0; i < 16; ++i) { px[i] = f[3 * i]; py[i] = f[3 * i + 1]; pz[i] = f[3 * i + 2]; }
    }
    float qx = pos[0], qy = pos[1], qz = pos[2];
    float lmax = -1.f; int lidx = 0;
#pragma unroll
    for (int i = 0; i < 16; ++i) {
        float dx = __fsub_rn(px[i], qx), dy = __fsub_rn(py[i], qy), dz = __fsub_rn(pz[i], qz);
        d[i] = __fadd_rn(__fadd_rn(__fmul_rn(dx, dx), __fmul_rn(dy, dy)), __fmul_rn(dz, dz));
        if (d[i] > lmax) { lmax = d[i]; lidx = i; }
    }
    if (t == 0) g_idx[0] = 0;

    __shared__ u64 warpK[16];
    __shared__ u64 winK;
    const int lane = t & 63, wid = t >> 6;

    for (int it = 1; it < S_OUT; ++it) {
        u64 key = ((u64)__float_as_uint(lmax) << 32) | (u32)(~(u32)(t * 16 + lidx));
#pragma unroll
        for (int off = 32; off >= 1; off >>= 1) {
            u64 o = __shfl_down(key, off);
            key = (o > key) ? o : key;
        }
        if (lane == 0) warpK[wid] = key;
        __syncthreads();                                   // b1
        if (wid == 0) {
            u64 k2 = (lane < 16) ? warpK[lane] : 0ull;
#pragma unroll
            for (int off = 8; off >= 1; off >>= 1) {
                u64 o = __shfl_down(k2, off);
                k2 = (o > k2) ? o : k2;
            }
            if (lane == 0) winK = k2;
        }
        __syncthreads();                                   // b2
        int wsel = (int)(~(u32)(winK & 0xffffffffu)) & (N_PTS - 1);   // clamp = fault guard
        if (t == 0) g_idx[it] = wsel;
        float wx = pos[3 * wsel], wy = pos[3 * wsel + 1], wz = pos[3 * wsel + 2];
        lmax = -1.f; lidx = 0;
#pragma unroll
        for (int i = 0; i < 16; ++i) {
            float dx = __fsub_rn(px[i], wx), dy = __fsub_rn(py[i], wy), dz = __fsub_rn(pz[i], wz);
            float nd = __fadd_rn(__fadd_rn(__fmul_rn(dx, dx), __fmul_rn(dy, dy)), __fmul_rn(dz, dz));
            d[i] = fminf(d[i], nd);
            if (d[i] > lmax) { lmax = d[i]; lidx = i; }
        }
    }
}

// ---------------- ball query: k-nearest within radius (fully deterministic) ----------------
// d2 = (cs + ps) - 2*(c.p): cs/ps are numpy ufunc sums (no FMA, sequential);
// the dot is BLAS sgemm K=3 -> sequential FMA chain fma(cz,z, fma(cy,y, cx*x)).
// Candidate compaction: two-pass stripe scan + prefix sum -> cd2/cid in global
// index order on EVERY run (zero atomics anywhere in the pipeline).
__global__ __launch_bounds__(256) void radius_kernel(const float* __restrict__ pos,
                                                     float* __restrict__ outF) {
    const int s = blockIdx.x, t = threadIdx.x;
    __shared__ float cd2[CAP];
    __shared__ int   cid[CAP];
    __shared__ int   scan_s[256];
    __shared__ u64   red[256];

    const int selfI = g_idx[s] & (N_PTS - 1);
    float cx = pos[3 * selfI], cy = pos[3 * selfI + 1], cz = pos[3 * selfI + 2];
    if (t < 3) { float v = pos[3 * selfI + t]; g_cen[3 * s + t] = v; outF[OUT_CEN + 3 * s + t] = v; }
    if (t == 3) outF[OUT_BATCH + s] = 0.0f;                // batch int32 zeros == f32 0 bits
    float cs = __fadd_rn(__fadd_rn(__fmul_rn(cx, cx), __fmul_rn(cy, cy)), __fmul_rn(cz, cz));

    // pass 1: count in-ball points in stripe [64t, 64t+64)
    const int p0 = t * 64;
    int c = 0;
    for (int i = 0; i < 64; ++i) {
        int p = p0 + i;
        float x = pos[3 * p], y = pos[3 * p + 1], z = pos[3 * p + 2];
        float ps = __fadd_rn(__fadd_rn(__fmul_rn(x, x), __fmul_rn(y, y)), __fmul_rn(z, z));
        float dt = __fmaf_rn(cz, z, __fmaf_rn(cy, y, __fmul_rn(cx, x)));   // BLAS K=3 chain
        float d2 = __fsub_rn(__fadd_rn(cs, ps), __fmul_rn(2.0f, dt));
        c += (d2 <= 0.04f) ? 1 : 0;                        // f32(0.2*0.2) bitwise
    }
    // inclusive prefix sum over 256 thread counts (Hillis-Steele)
    scan_s[t] = c;
    __syncthreads();
#pragma unroll
    for (int off = 1; off < 256; off <<= 1) {
        int v = scan_s[t] + ((t >= off) ? scan_s[t - off] : 0);
        __syncthreads();
        scan_s[t] = v;
        __syncthreads();
    }
    const int total = scan_s[255];
    int w = scan_s[t] - c;                                 // exclusive base
    // pass 2: recompute (bitwise-identical) and write compacted, index-ordered
    for (int i = 0; i < 64; ++i) {
        int p = p0 + i;
        float x = pos[3 * p], y = pos[3 * p + 1], z = pos[3 * p + 2];
        float ps = __fadd_rn(__fadd_rn(__fmul_rn(x, x), __fmul_rn(y, y)), __fmul_rn(z, z));
        float dt = __fmaf_rn(cz, z, __fmaf_rn(cy, y, __fmul_rn(cx, x)));
        float d2 = __fsub_rn(__fadd_rn(cs, ps), __fmul_rn(2.0f, dt));
        if (d2 <= 0.04f) {
            if (w < CAP) { cd2[w] = d2; cid[w] = p; }
            ++w;
        }
    }
    __syncthreads();
    const int n = min(total, CAP);
    if (n <= K_NB) {
        if (t < K_NB) g_col[s * K_NB + t] = (t < n) ? cid[t] : selfI;
        if (t == 0) g_cnt[s] = n;
    } else {
        // K smallest by (d2, idx) lexicographic == stable top_k neighbor set
        for (int k = 0; k < K_NB; ++k) {
            u64 best = ~0ull;
            for (int q = t; q < n; q += 256) {
                u32 fb = __float_as_uint(cd2[q]);
                fb = (fb >> 31) ? ~fb : (fb | 0x80000000u);   // total order incl. negative d2
                u64 key = ((u64)fb << 32) | (u32)cid[q];
                best = best < key ? best : key;
            }
            red[t] = best;
            __syncthreads();
#pragma unroll
            for (int s2 = 128; s2 > 0; s2 >>= 1) {
                if (t < s2) { u64 o = red[t + s2]; if (o < red[t]) red[t] = o; }
                __syncthreads();
            }
            u64 win = red[0];
            int wi = (int)(u32)(win & 0xffffffffu);
            if (t == 0) g_col[s * K_NB + k] = wi;
            for (int q = t; q < n; q += 256)
                if (cid[q] == wi) cd2[q] = __uint_as_float(0x7f7fffffu);   // FLT_MAX
            __syncthreads();
        }
        if (t == 0) g_cnt[s] = K_NB;
    }
}

// ---------------- fused 3-layer MLP + masked max pool (all f32) ----------------
// Shared layout (floats): [h2s 0..4224) [inp 4224..6400) [h1s 6400..10624)
// h3 (stride 260, 8320 floats) ALIASES [4224..12544) -- inp/h1s are dead by then.
#define SM_H2  0
#define SM_INP 4224
#define SM_H1  6400
#define SM_H3  4224
#define SM_TOT 12544

__global__ __launch_bounds__(256) void mlp_kernel(const float* __restrict__ x,
                                                  const float* __restrict__ pos,
                                                  const float* __restrict__ W1,
                                                  const float* __restrict__ b1,
                                                  const float* __restrict__ W2,
                                                  const float* __restrict__ b2,
                                                  const float* __restrict__ W3,
                                                  const float* __restrict__ b3,
                                                  float* __restrict__ outF) {
    const int s = blockIdx.x, t = threadIdx.x;
    __shared__ __align__(16) float smem[SM_TOT];
    __shared__ int cols[32];
    float* inp = smem + SM_INP;     // [32][68]
    float* h1s = smem + SM_H1;      // [32][132]
    float* h2s = smem + SM_H2;      // [32][132]
    float* h3  = smem + SM_H3;      // [32][260]

    const int n = g_cnt[s];
    if (t < 32) cols[t] = g_col[s * K_NB + t] & (N_PTS - 1);   // fault guard
    __syncthreads();

    // stage inp = [x_j (64) | pos_j - center (3) | 0]
    {
        const int r = t >> 3, sg = t & 7;
        const float4* x4 = (const float4*)x;
        float4 v1 = x4[cols[r] * 16 + sg * 2];
        float4 v2 = x4[cols[r] * 16 + sg * 2 + 1];
        *(float4*)&inp[r * 68 + sg * 8]     = v1;
        *(float4*)&inp[r * 68 + sg * 8 + 4] = v2;
    }
    if (t < 32) {
        int j = cols[t];
        inp[t * 68 + 64] = __fsub_rn(pos[3 * j],     g_cen[3 * s]);
        inp[t * 68 + 65] = __fsub_rn(pos[3 * j + 1], g_cen[3 * s + 1]);
        inp[t * 68 + 66] = __fsub_rn(pos[3 * j + 2], g_cen[3 * s + 2]);
        inp[t * 68 + 67] = 0.f;
    }
    __syncthreads();

    const int r = t & 31, cg = t >> 5;
    // ---- layer 1: [32,67] @ [67,128] (+b, relu) ----
    {
        const int c0 = cg * 16;
        float acc[16];
#pragma unroll
        for (int j = 0; j < 16; ++j) acc[j] = 0.f;
        for (int i0 = 0; i0 < 64; i0 += 4) {
            float4 a4 = *(const float4*)&inp[r * 68 + i0];
#pragma unroll
            for (int q = 0; q < 4; ++q) {
                float a = (q == 0) ? a4.x : (q == 1) ? a4.y : (q == 2) ? a4.z : a4.w;
                const float* wr = &W1[(i0 + q) * 128 + c0];
#pragma unroll
                for (int m = 0; m < 4; ++m) {
                    float4 w = *(const float4*)(wr + 4 * m);
                    acc[4 * m]     += a * w.x; acc[4 * m + 1] += a * w.y;
                    acc[4 * m + 2] += a * w.z; acc[4 * m + 3] += a * w.w;
                }
            }
        }
#pragma unroll
        for (int q = 0; q < 3; ++q) {                       // rows 64..66 (rel xyz)
            float a = inp[r * 68 + 64 + q];
            const float* wr = &W1[(64 + q) * 128 + c0];
#pragma unroll
            for (int m = 0; m < 4; ++m) {
                float4 w = *(const float4*)(wr + 4 * m);
                acc[4 * m]     += a * w.x; acc[4 * m + 1] += a * w.y;
                acc[4 * m + 2] += a * w.z; acc[4 * m + 3] += a * w.w;
            }
        }
#pragma unroll
        for (int j = 0; j < 16; ++j) h1s[r * 132 + c0 + j] = fmaxf(acc[j] + b1[c0 + j], 0.f);
    }
    __syncthreads();
    // ---- layer 2: [32,128] @ [128,128] (+b, relu) ----
    {
        const int c0 = cg * 16;
        float acc[16];
#pragma unroll
        for (int j = 0; j < 16; ++j) acc[j] = 0.f;
        for (int i0 = 0; i0 < 128; i0 += 4) {
            float4 a4 = *(const float4*)&h1s[r * 132 + i0];
#pragma unroll
            for (int q = 0; q < 4; ++q) {
                float a = (q == 0) ? a4.x : (q == 1) ? a4.y : (q == 2) ? a4.z : a4.w;
                const float* wr = &W2[(i0 + q) * 128 + c0];
#pragma unroll
                for (int m = 0; m < 4; ++m) {
                    float4 w = *(const float4*)(wr + 4 * m);
                    acc[4 * m]     += a * w.x; acc[4 * m + 1] += a * w.y;
                    acc[4 * m + 2] += a * w.z; acc[4 * m + 3] += a * w.w;
                }
            }
        }
#pragma unroll
        for (int j = 0; j < 16; ++j) h2s[r * 132 + c0 + j] = fmaxf(acc[j] + b2[c0 + j], 0.f);
    }
    __syncthreads();
    // ---- layer 3: [32,128] @ [128,256] (+b) -> h3 (aliases inp/h1s, both dead) ----
    {
        const int c0 = cg * 32;
        float acc[32];
#pragma unroll
        for (int j = 0; j < 32; ++j) acc[j] = 0.f;
        for (int i0 = 0; i0 < 128; i0 += 4) {
            float4 a4 = *(const float4*)&h2s[r * 132 + i0];
#pragma unroll
            for (int q = 0; q < 4; ++q) {
                float a = (q == 0) ? a4.x : (q == 1) ? a4.y : (q == 2) ? a4.z : a4.w;
                const float* wr = &W3[(i0 + q) * 256 + c0];
#pragma unroll
                for (int m = 0; m < 8; ++m) {
                    float4 w = *(const float4*)(wr + 4 * m);
                    acc[4 * m]     += a * w.x; acc[4 * m + 1] += a * w.y;
                    acc[4 * m + 2] += a * w.z; acc[4 * m + 3] += a * w.w;
                }
            }
        }
        __syncthreads();                                   // h2s reads done before alias write
#pragma unroll
        for (int j = 0; j < 32; ++j) h3[r * 260 + c0 + j] = acc[j] + b3[c0 + j];
    }
    __syncthreads();
    // ---- masked max over valid neighbors (rows 0..n-1 = exactly the valid set) ----
    {
        float m = h3[t];                        // n >= 1 always (self in own ball)
        for (int rr = 1; rr < n; ++rr) m = fmaxf(m, h3[rr * 260 + t]);
        outF[s * 256 + t] = m;
    }
}

extern "C" void kernel_launch(void* const* d_in, const int* in_sizes, int n_in,
                              void* d_out, int out_size, void* d_ws, size_t ws_size,
                              hipStream_t stream) {
    const float* x   = (const float*)d_in[0];
    const float* pos = (const float*)d_in[1];
    // d_in[2] = batch (int32, all zeros) — batch output written as zeros directly
    const float* W1 = (const float*)d_in[3]; const float* b1 = (const float*)d_in[4];
    const float* W2 = (const float*)d_in[5]; const float* b2 = (const float*)d_in[6];
    const float* W3 = (const float*)d_in[7]; const float* b3 = (const float*)d_in[8];
    float* outF = (float*)d_out;
    (void)d_ws; (void)ws_size; (void)in_sizes; (void)n_in; (void)out_size;

    hipLaunchKernelGGL(fps_kernel, dim3(1), dim3(1024), 0, stream, pos);
    hipLaunchKernelGGL(radius_kernel, dim3(S_OUT), dim3(256), 0, stream, pos, outF);
    hipLaunchKernelGGL(mlp_kernel, dim3(S_OUT), dim3(256), 0, stream,
                       x, pos, W1, b1, W2, b2, W3, b3, outF);
}